// Round 19
// baseline (1863.518 us; speedup 1.0000x reference)
//
#include <hip/hip_runtime.h>

#define Bq 128
#define Tq 256
#define Dq 512
#define Hq 1024
#define N4H 4096
#define NWG 256          // 1 wg per CU, 32 per XCD (forced by ~152KB static LDS)
#define NTHR 1024        // 16 waves: (ug in [0,4)) x (kq in [0,4))
#define BHq (Bq * Hq)

typedef __attribute__((ext_vector_type(8))) short bf16x8;
typedef __attribute__((ext_vector_type(4))) float f32x4;

static __device__ __forceinline__ unsigned short f2bf(float x) {
    unsigned int u = __builtin_bit_cast(unsigned int, x);
    u = (u + 0x7FFFu + ((u >> 16) & 1u)) >> 16;
    return (unsigned short)u;
}
static __device__ __forceinline__ float bf2f(unsigned short h) {
    unsigned int u = ((unsigned int)h) << 16;
    return __builtin_bit_cast(float, u);
}
static __device__ __forceinline__ float sigm(float x) { return 1.f / (1.f + __expf(-x)); }
static __device__ __forceinline__ float tanh_f(float x) { return 2.f / (1.f + __expf(-2.f * x)) - 1.f; }

// ---- pack weights into MFMA-fragment order:
// Wp[s][c][wlc][kg][8e]  (ushort offset = (((s*48+c)*128+wlc)*4+kg)*8)
__global__ __launch_bounds__(256) void pack_w(const float* __restrict__ Kw,
                                              const float* __restrict__ Rw,
                                              unsigned short* __restrict__ Wp) {
    __shared__ float tile[32][33];
    int n0 = blockIdx.x * 32;  // gate-col base
    int k0 = blockIdx.y * 32;  // K base
    int tx = threadIdx.x, ty = threadIdx.y;  // 32 x 8
#pragma unroll
    for (int i = 0; i < 32; i += 8) {
        int k = k0 + ty + i;
        float v = (k < Dq) ? Kw[(size_t)k * N4H + n0 + tx] : Rw[(size_t)(k - Dq) * N4H + n0 + tx];
        tile[ty + i][tx] = v;
    }
    __syncthreads();
    if (ty < 4) {
        int s = (n0 & 1023) >> 5;
        int q = n0 >> 10;
        int c = k0 >> 5;
        int wlc = q * 32 + tx;
        bf16x8 v;
#pragma unroll
        for (int e = 0; e < 8; ++e) v[e] = (short)f2bf(tile[ty * 8 + e][tx]);
        *(bf16x8*)(Wp + ((((size_t)s * 48 + c) * 128 + wlc) * 4 + ty) * 8) = v;
    }
}

// ---- cast + transpose input to bf16 [T][B][D]
__global__ __launch_bounds__(256) void pack_x(const float* __restrict__ X,
                                              unsigned short* __restrict__ Xb) {
    int gid = blockIdx.x * 256 + threadIdx.x;
    int dc = gid & 63;
    int t = (gid >> 6) & 255;
    int b = gid >> 14;
    const float* src = X + ((size_t)b * Tq + t) * Dq + dc * 8;
    float4 v0 = *(const float4*)src;
    float4 v1 = *(const float4*)(src + 4);
    bf16x8 r;
    r[0] = (short)f2bf(v0.x); r[1] = (short)f2bf(v0.y);
    r[2] = (short)f2bf(v0.z); r[3] = (short)f2bf(v0.w);
    r[4] = (short)f2bf(v1.x); r[5] = (short)f2bf(v1.y);
    r[6] = (short)f2bf(v1.z); r[7] = (short)f2bf(v1.w);
    *(bf16x8*)(Xb + ((size_t)t * Bq + b) * Dq + dc * 8) = r;
}

// ---- zero h buffer 0 + barrier/topology/flag state (re-run every launch)
__global__ __launch_bounds__(256) void init_ws(unsigned short* __restrict__ Hb,
                                               unsigned* __restrict__ bar) {
    int i = blockIdx.x * 256 + threadIdx.x;  // 131072 = h buffer 0
    Hb[i] = 0;
    if (i < 17408) bar[i] = 0;
}

// bar layout (u32, 128B-separated lines):
//   cnt[x]      @ x*32            : per-XCD step counter (atomic adds)
//   topo[x]     @ 512 + x*32      : registration tickets (agent, one-time)
//   flag[x][s]  @ 1024 + (x*32+s)*32 : per-wg step flags (1 poller each)
__global__ __launch_bounds__(NTHR, 4) void lstm_persist(
    const unsigned short* __restrict__ Wp,
    const unsigned short* __restrict__ Xb,
    const float* __restrict__ bias,
    unsigned short* __restrict__ Hb,
    const float* __restrict__ dw,
    const float* __restrict__ db,
    float* __restrict__ out,
    unsigned* __restrict__ bar) {
    // STATIC LDS: weights 122,880 B + redbuf 32,768 B = 155,648 B -> 1 wg/CU
    __shared__ unsigned short Wl[12 * 128 * 40];  // h-chunks 16..27, padded stride 40
    // redbuf[w][g][kq][u'] : u' = (u + 8*(w>>2)) & 31  -> conflict-free both sides
    __shared__ float redbuf[16 * 4 * 4 * 32];
    __shared__ float red[16];
    __shared__ int s_topo[4];  // slot, rbase, myxcd, mytot

    const int tid = threadIdx.x;
    const int wave = tid >> 6;
    const int lane = tid & 63;
    const int ug = wave & 3;
    const int kq = wave >> 2;
    const int c16 = lane & 15;
    const int kg = lane >> 4;

    // ---- startup: XCD topology + slot ticket
    if (tid == 0) {
        int xcd;
        asm volatile("s_getreg_b32 %0, hwreg(HW_REG_XCC_ID)" : "=s"(xcd));
        xcd &= 15;
        unsigned slot = __hip_atomic_fetch_add(&bar[512 + xcd * 32], 1u,
                                               __ATOMIC_RELAXED, __HIP_MEMORY_SCOPE_AGENT);
        for (;;) {
            unsigned sum = 0;
            for (int i = 0; i < 16; ++i)
                sum += __hip_atomic_load(&bar[512 + i * 32], __ATOMIC_RELAXED, __HIP_MEMORY_SCOPE_AGENT);
            if (sum == NWG) break;
            __builtin_amdgcn_s_sleep(2);
        }
        int rank = 0, nx = 0, tot = 0;
        for (int i = 0; i < 16; ++i) {
            unsigned v = __hip_atomic_load(&bar[512 + i * 32], __ATOMIC_RELAXED, __HIP_MEMORY_SCOPE_AGENT);
            if (v) { if (i < xcd) rank++; nx++; }
            if (i == xcd) tot = (int)v;
        }
        s_topo[0] = (int)slot;
        s_topo[1] = rank * (Bq / nx);
        s_topo[2] = xcd;
        s_topo[3] = tot;
    }
    __syncthreads();
    const int slot = s_topo[0];
    const int rbase = s_topo[1];
    const int myxcd = s_topo[2];
    const unsigned mytot = (unsigned)s_topo[3];

    const size_t gbase = (size_t)slot * 48 * 4096;

    // ---- load LDS h-chunks 16..27
    for (int it = tid; it < 6144; it += NTHR) {
        int kgx = it & 3;
        int wlcx = (it >> 2) & 127;
        int cc = it >> 9;
        *(bf16x8*)(Wl + ((cc * 128 + wlcx) * 40 + kgx * 8)) =
            *(const bf16x8*)(Wp + gbase + (size_t)(16 + cc) * 4096 + ((size_t)wlcx * 4 + kgx) * 8);
    }

    const int wlc0 = (c16 >> 3) * 32 + ug * 8 + (c16 & 7);
    const int wlc1 = wlc0 + 64;
    const int arow = rbase + c16;
    const int uu = lane & 31;  // epilogue unit (lanes<32 active)
    float biasv[4];
#pragma unroll
    for (int g = 0; g < 4; ++g) biasv[g] = bias[g * Hq + slot * 32 + uu];

    // ---- time-invariant B fragments -> registers/AGPRs, ONCE, laundered opaque
    bf16x8 pb0[5], pb1[5], xb0[4], xb1[4];
#pragma unroll
    for (int i = 0; i < 5; ++i) {
        int c = kq + 4 * (7 + i);
        const unsigned short* gp = Wp + gbase + (size_t)c * 4096;
        pb0[i] = *(const bf16x8*)(gp + (wlc0 * 4 + kg) * 8);
        pb1[i] = *(const bf16x8*)(gp + (wlc1 * 4 + kg) * 8);
        asm volatile("" : "+v"(pb0[i]));
        asm volatile("" : "+v"(pb1[i]));
    }
#pragma unroll
    for (int i = 0; i < 4; ++i) {
        int c = kq + 4 * i;
        const unsigned short* gp = Wp + gbase + (size_t)c * 4096;
        xb0[i] = *(const bf16x8*)(gp + (wlc0 * 4 + kg) * 8);
        xb1[i] = *(const bf16x8*)(gp + (wlc1 * 4 + kg) * 8);
        asm volatile("" : "+v"(xb0[i]));
        asm volatile("" : "+v"(xb1[i]));
    }

    float creg0 = 0.f;  // c-state: (row = rbase+wave, unit = uu), lanes<32

    __syncthreads();

    // ---- x-part partial accs for t=0 (pinned x-B, only A streams)
    f32x4 xa0 = {0.f, 0.f, 0.f, 0.f};
    f32x4 xa1 = {0.f, 0.f, 0.f, 0.f};
    {
        const unsigned short* xb = Xb + (size_t)arow * Dq + kg * 8;
#pragma unroll
        for (int i = 0; i < 4; ++i) {
            bf16x8 A = *(const bf16x8*)(xb + (kq + 4 * i) * 32);
            xa0 = __builtin_amdgcn_mfma_f32_16x16x32_bf16(A, xb0[i], xa0, 0, 0, 0);
            xa1 = __builtin_amdgcn_mfma_f32_16x16x32_bf16(A, xb1[i], xa1, 0, 0, 0);
        }
    }

    const unsigned long long cntaddr = (unsigned long long)(bar + myxcd * 32);
    const unsigned long long myflag = (unsigned long long)(bar + 1024 + (myxcd * 32 + slot) * 32);

    for (int t = 0; t < Tq; ++t) {
        const unsigned short* Hcur = Hb + (size_t)t * BHq;
        unsigned short* Hnxt = Hb + (size_t)(t + 1) * BHq;
        const unsigned short* hb = Hcur + (size_t)arow * Hq + kg * 8;

        f32x4 acc0 = xa0, acc1 = xa1;

        // h-part GEMM: reg-held B (chunks 28..47 slice) + LDS B (chunks 16..27 slice)
#pragma unroll
        for (int i = 0; i < 5; ++i) {
            int c = kq + 4 * (7 + i);
            bf16x8 A = *(const bf16x8*)(hb + (c * 32 - Dq));
            acc0 = __builtin_amdgcn_mfma_f32_16x16x32_bf16(A, pb0[i], acc0, 0, 0, 0);
            acc1 = __builtin_amdgcn_mfma_f32_16x16x32_bf16(A, pb1[i], acc1, 0, 0, 0);
        }
#pragma unroll
        for (int i = 4; i < 7; ++i) {
            int c = kq + 4 * i;
            bf16x8 A = *(const bf16x8*)(hb + (c * 32 - Dq));
            const unsigned short* lp = Wl + ((c - 16) * 128) * 40 + kg * 8;
            bf16x8 B0 = *(const bf16x8*)(lp + wlc0 * 40);
            bf16x8 B1 = *(const bf16x8*)(lp + wlc1 * 40);
            acc0 = __builtin_amdgcn_mfma_f32_16x16x32_bf16(A, B0, acc0, 0, 0, 0);
            acc1 = __builtin_amdgcn_mfma_f32_16x16x32_bf16(A, B1, acc1, 0, 0, 0);
        }

        // ALL waves write partials, bank-swizzled:
        // redbuf[((w*4+g)*4+kq)*32 + ((u + 8*kg)&31)]  (w = kg*4+r, so kg = w>>2)
#pragma unroll
        for (int r = 0; r < 4; ++r) {
            int w = kg * 4 + r;
            int u = ug * 8 + (c16 & 7);
            int g0 = (c16 >> 3);
            int up = (u + 8 * kg) & 31;
            redbuf[((w * 4 + g0) * 4 + kq) * 32 + up] = acc0[r];
            redbuf[((w * 4 + g0 + 2) * 4 + kq) * 32 + up] = acc1[r];
        }
        __syncthreads();  // (A) partials visible

        // ---- ALL-WAVE epilogue: wave w = row rbase+wave, lane uu<32 = unit uu.
        if (lane < 32) {
            const int up = (uu + 8 * (wave >> 2)) & 31;
            float z[4];
#pragma unroll
            for (int g = 0; g < 4; ++g) {
                z[g] = redbuf[((wave * 4 + g) * 4 + 0) * 32 + up] +
                       redbuf[((wave * 4 + g) * 4 + 1) * 32 + up] +
                       redbuf[((wave * 4 + g) * 4 + 2) * 32 + up] +
                       redbuf[((wave * 4 + g) * 4 + 3) * 32 + up] + biasv[g];
            }
            float gi = sigm(z[0]);
            float gf = sigm(z[1]);
            float gg = tanh_f(z[2]);
            float go = sigm(z[3]);
            float cn = gf * creg0 + gi * gg;
            creg0 = cn;
            float hn = go * tanh_f(cn);
            unsigned hb16 = (unsigned)f2bf(hn);
            unsigned pv = (unsigned)__shfl_xor((int)hb16, 1, 64);
            if (!(uu & 1)) {
                unsigned word = (hb16 & 0xffffu) | (pv << 16);
                unsigned long long a =
                    (unsigned long long)(Hnxt + (size_t)(rbase + wave) * Hq + slot * 32 + uu);
                asm volatile("global_store_dword %0, %1, off sc0" ::"v"(a), "v"(word) : "memory");
            }
        }

        __syncthreads();  // (B) all h sc0-stores drained (per-wave vmcnt)

        // ---- arrive: atomic add (fire-and-forget)
        if (tid == 0) {
            asm volatile("global_atomic_add %0, %1, off" ::"v"(cntaddr), "v"(1u) : "memory");
        }

        // ---- ALL waves: x-part prefetch for t+1 (overlaps barrier wait)
        if (t + 1 < Tq) {
            const unsigned short* xb = Xb + ((size_t)(t + 1) * Bq + arow) * Dq + kg * 8;
            xa0 = (f32x4){0.f, 0.f, 0.f, 0.f};
            xa1 = (f32x4){0.f, 0.f, 0.f, 0.f};
#pragma unroll
            for (int i = 0; i < 4; ++i) {
                bf16x8 A = *(const bf16x8*)(xb + (kq + 4 * i) * 32);
                xa0 = __builtin_amdgcn_mfma_f32_16x16x32_bf16(A, xb0[i], xa0, 0, 0, 0);
                xa1 = __builtin_amdgcn_mfma_f32_16x16x32_bf16(A, xb1[i], xa1, 0, 0, 0);
            }
        }

        // ---- wait: atomic-add-0 sc0 probes (RMW executes at L2, always fresh)
        if (tid == 0) {
            if (slot == 0) {
                const unsigned target = mytot * (unsigned)(t + 1);
                for (;;) {
                    unsigned old;
                    asm volatile("global_atomic_add %0, %1, %2, off sc0\n\ts_waitcnt vmcnt(0)"
                                 : "=v"(old)
                                 : "v"(cntaddr), "v"(0u)
                                 : "memory");
                    if (old >= target) break;
                    __builtin_amdgcn_s_sleep(1);
                }
                unsigned stepv = (unsigned)(t + 1);
#pragma unroll
                for (int s = 1; s < 32; ++s) {
                    unsigned long long fa = (unsigned long long)(bar + 1024 + (myxcd * 32 + s) * 32);
                    asm volatile("global_store_dword %0, %1, off sc0" ::"v"(fa), "v"(stepv) : "memory");
                }
            } else {
                for (;;) {
                    unsigned fv;
                    asm volatile("global_atomic_add %0, %1, %2, off sc0\n\ts_waitcnt vmcnt(0)"
                                 : "=v"(fv)
                                 : "v"(myflag), "v"(0u)
                                 : "memory");
                    if (fv >= (unsigned)(t + 1)) break;
                    __builtin_amdgcn_s_sleep(1);
                }
            }
            asm volatile("" ::: "memory");
        }
        __syncthreads();  // (C)
    }

    // ---- dense head: slots 0..15 each handle one local batch row
    if (slot < 16) {
        const int b = rbase + slot;
        const unsigned short* hl = Hb + (size_t)Tq * BHq + (size_t)b * Hq;
        float s = bf2f(hl[tid]) * dw[tid];  // Hq == NTHR
#pragma unroll
        for (int off = 32; off > 0; off >>= 1) s += __shfl_down(s, off, 64);
        if (lane == 0) red[wave] = s;
        __syncthreads();
        if (tid == 0) {
            float tot = db[0];
#pragma unroll
            for (int wv = 0; wv < 16; ++wv) tot += red[wv];
            out[b] = 1.f / (1.f + __expf(-tot));
        }
    }
}

extern "C" void kernel_launch(void* const* d_in, const int* in_sizes, int n_in,
                              void* d_out, int out_size, void* d_ws, size_t ws_size,
                              hipStream_t stream) {
    const float* X = (const float*)d_in[0];
    const float* Kw = (const float*)d_in[1];
    const float* Rw = (const float*)d_in[2];
    const float* bias = (const float*)d_in[3];
    const float* dw = (const float*)d_in[4];
    const float* db = (const float*)d_in[5];
    float* out = (float*)d_out;
    char* ws = (char*)d_ws;

    // workspace layout:
    //   Wp  bf16 fragment-packed [32][48][128][4][8]  @ 0           (12,582,912)
    //   Xb  bf16 [256][128][512]                      @ 12,582,912  (33,554,432)
    //   Hb  bf16 [257][128][1024] rotating            @ 46,137,344  (67,371,008)
    //   bar u32 [17408]                               @ 113,508,352 (69,632)
    unsigned short* Wp = (unsigned short*)(ws);
    unsigned short* Xb = (unsigned short*)(ws + 12582912);
    unsigned short* Hb = (unsigned short*)(ws + 46137344);
    unsigned* bar = (unsigned*)(ws + 113508352);

    pack_w<<<dim3(128, 48), dim3(32, 8), 0, stream>>>(Kw, Rw, Wp);
    pack_x<<<8192, 256, 0, stream>>>(X, Xb);
    init_ws<<<512, 256, 0, stream>>>(Hb, bar);

    lstm_persist<<<NWG, NTHR, 0, stream>>>(Wp, Xb, bias, Hb, dw, db, out, bar);
}

// Round 20
// 1670.168 us; speedup vs baseline: 1.1158x; 1.1158x over previous
//
#include <hip/hip_runtime.h>

#define Bq 128
#define Tq 256
#define Dq 512
#define Hq 1024
#define N4H 4096
#define NWG 256          // 1 wg per CU, 32 per XCD (forced by ~153KB static LDS)
#define NTHR 1024        // 16 waves: (ug in [0,4)) x (kq in [0,4))
#define BHq (Bq * Hq)    // one h buffer: 131072 elems (layout [32 slots][128 b][32 u])

typedef __attribute__((ext_vector_type(8))) short bf16x8;
typedef __attribute__((ext_vector_type(4))) float f32x4;

static __device__ __forceinline__ unsigned short f2bf(float x) {
    unsigned int u = __builtin_bit_cast(unsigned int, x);
    u = (u + 0x7FFFu + ((u >> 16) & 1u)) >> 16;
    return (unsigned short)u;
}
static __device__ __forceinline__ float bf2f(unsigned short h) {
    unsigned int u = ((unsigned int)h) << 16;
    return __builtin_bit_cast(float, u);
}
static __device__ __forceinline__ float sigm(float x) { return 1.f / (1.f + __expf(-x)); }
static __device__ __forceinline__ float tanh_f(float x) { return 2.f / (1.f + __expf(-2.f * x)) - 1.f; }

// ---- pack weights into MFMA-fragment order:
// Wp[s][c][wlc][kg][8e]  (ushort offset = (((s*48+c)*128+wlc)*4+kg)*8)
__global__ __launch_bounds__(256) void pack_w(const float* __restrict__ Kw,
                                              const float* __restrict__ Rw,
                                              unsigned short* __restrict__ Wp) {
    __shared__ float tile[32][33];
    int n0 = blockIdx.x * 32;  // gate-col base
    int k0 = blockIdx.y * 32;  // K base
    int tx = threadIdx.x, ty = threadIdx.y;  // 32 x 8
#pragma unroll
    for (int i = 0; i < 32; i += 8) {
        int k = k0 + ty + i;
        float v = (k < Dq) ? Kw[(size_t)k * N4H + n0 + tx] : Rw[(size_t)(k - Dq) * N4H + n0 + tx];
        tile[ty + i][tx] = v;
    }
    __syncthreads();
    if (ty < 4) {
        int s = (n0 & 1023) >> 5;
        int q = n0 >> 10;
        int c = k0 >> 5;
        int wlc = q * 32 + tx;
        bf16x8 v;
#pragma unroll
        for (int e = 0; e < 8; ++e) v[e] = (short)f2bf(tile[ty * 8 + e][tx]);
        *(bf16x8*)(Wp + ((((size_t)s * 48 + c) * 128 + wlc) * 4 + ty) * 8) = v;
    }
}

// ---- cast + transpose input to bf16 [T][B][D]
__global__ __launch_bounds__(256) void pack_x(const float* __restrict__ X,
                                              unsigned short* __restrict__ Xb) {
    int gid = blockIdx.x * 256 + threadIdx.x;
    int dc = gid & 63;
    int t = (gid >> 6) & 255;
    int b = gid >> 14;
    const float* src = X + ((size_t)b * Tq + t) * Dq + dc * 8;
    float4 v0 = *(const float4*)src;
    float4 v1 = *(const float4*)(src + 4);
    bf16x8 r;
    r[0] = (short)f2bf(v0.x); r[1] = (short)f2bf(v0.y);
    r[2] = (short)f2bf(v0.z); r[3] = (short)f2bf(v0.w);
    r[4] = (short)f2bf(v1.x); r[5] = (short)f2bf(v1.y);
    r[6] = (short)f2bf(v1.z); r[7] = (short)f2bf(v1.w);
    *(bf16x8*)(Xb + ((size_t)t * Bq + b) * Dq + dc * 8) = r;
}

// ---- zero h buffer 0 + barrier/topology/flag state (re-run every launch)
__global__ __launch_bounds__(256) void init_ws(unsigned short* __restrict__ Hb,
                                               unsigned* __restrict__ bar) {
    int i = blockIdx.x * 256 + threadIdx.x;  // 131072 = h buffer 0
    Hb[i] = 0;
    if (i < 17408) bar[i] = 0;
}

// bar layout (u32, 128B-separated lines):
//   cnt[x]      @ x*32            : per-XCD step counter (atomic adds)
//   topo[x]     @ 512 + x*32      : registration tickets (agent, one-time)
//   flag[x][s]  @ 1024 + (x*32+s)*32 : per-wg step flags (1 poller each)
__global__ __launch_bounds__(NTHR, 4) void lstm_persist(
    const unsigned short* __restrict__ Wp,
    const unsigned short* __restrict__ Xb,
    const float* __restrict__ bias,
    unsigned short* __restrict__ Hb,
    const float* __restrict__ dw,
    const float* __restrict__ db,
    float* __restrict__ out,
    unsigned* __restrict__ bar) {
    // STATIC LDS: weights 122,880 + redbuf 32,768 + hstage 1,024 = ~156.7KB -> 1 wg/CU
    __shared__ unsigned short Wl[12 * 128 * 40];  // h-chunks 16..27, padded stride 40
    __shared__ float redbuf[16 * 4 * 4 * 32];     // [w][g][kq][u'], swizzled
    __shared__ unsigned hstage[256];              // staged h: [row16][u32 pair x16] = 1024B
    __shared__ float red[16];
    __shared__ int s_topo[4];  // slot, rbase, myxcd, mytot

    const int tid = threadIdx.x;
    const int wave = tid >> 6;
    const int lane = tid & 63;
    const int ug = wave & 3;
    const int kq = wave >> 2;
    const int c16 = lane & 15;
    const int kg = lane >> 4;

    // ---- startup: XCD topology + slot ticket
    if (tid == 0) {
        int xcd;
        asm volatile("s_getreg_b32 %0, hwreg(HW_REG_XCC_ID)" : "=s"(xcd));
        xcd &= 15;
        unsigned slot = __hip_atomic_fetch_add(&bar[512 + xcd * 32], 1u,
                                               __ATOMIC_RELAXED, __HIP_MEMORY_SCOPE_AGENT);
        for (;;) {
            unsigned sum = 0;
            for (int i = 0; i < 16; ++i)
                sum += __hip_atomic_load(&bar[512 + i * 32], __ATOMIC_RELAXED, __HIP_MEMORY_SCOPE_AGENT);
            if (sum == NWG) break;
            __builtin_amdgcn_s_sleep(2);
        }
        int rank = 0, nx = 0, tot = 0;
        for (int i = 0; i < 16; ++i) {
            unsigned v = __hip_atomic_load(&bar[512 + i * 32], __ATOMIC_RELAXED, __HIP_MEMORY_SCOPE_AGENT);
            if (v) { if (i < xcd) rank++; nx++; }
            if (i == xcd) tot = (int)v;
        }
        s_topo[0] = (int)slot;
        s_topo[1] = rank * (Bq / nx);
        s_topo[2] = xcd;
        s_topo[3] = tot;
    }
    __syncthreads();
    const int slot = s_topo[0];
    const int rbase = s_topo[1];
    const int myxcd = s_topo[2];
    const unsigned mytot = (unsigned)s_topo[3];

    const size_t gbase = (size_t)slot * 48 * 4096;

    // ---- load LDS h-chunks 16..27
    for (int it = tid; it < 6144; it += NTHR) {
        int kgx = it & 3;
        int wlcx = (it >> 2) & 127;
        int cc = it >> 9;
        *(bf16x8*)(Wl + ((cc * 128 + wlcx) * 40 + kgx * 8)) =
            *(const bf16x8*)(Wp + gbase + (size_t)(16 + cc) * 4096 + ((size_t)wlcx * 4 + kgx) * 8);
    }

    const int wlc0 = (c16 >> 3) * 32 + ug * 8 + (c16 & 7);
    const int wlc1 = wlc0 + 64;
    const int arow = rbase + c16;
    const int uu = lane & 31;  // epilogue unit (lanes<32 active)
    float biasv[4];
#pragma unroll
    for (int g = 0; g < 4; ++g) biasv[g] = bias[g * Hq + slot * 32 + uu];

    // ---- time-invariant B fragments -> registers/AGPRs, ONCE, laundered opaque
    bf16x8 pb0[5], pb1[5], xb0[4], xb1[4];
#pragma unroll
    for (int i = 0; i < 5; ++i) {
        int c = kq + 4 * (7 + i);
        const unsigned short* gp = Wp + gbase + (size_t)c * 4096;
        pb0[i] = *(const bf16x8*)(gp + (wlc0 * 4 + kg) * 8);
        pb1[i] = *(const bf16x8*)(gp + (wlc1 * 4 + kg) * 8);
        asm volatile("" : "+v"(pb0[i]));
        asm volatile("" : "+v"(pb1[i]));
    }
#pragma unroll
    for (int i = 0; i < 4; ++i) {
        int c = kq + 4 * i;
        const unsigned short* gp = Wp + gbase + (size_t)c * 4096;
        xb0[i] = *(const bf16x8*)(gp + (wlc0 * 4 + kg) * 8);
        xb1[i] = *(const bf16x8*)(gp + (wlc1 * 4 + kg) * 8);
        asm volatile("" : "+v"(xb0[i]));
        asm volatile("" : "+v"(xb1[i]));
    }

    float creg0 = 0.f;  // c-state: (row = rbase+wave, unit = uu), lanes<32

    __syncthreads();

    // ---- x-part partial accs for t=0 (pinned x-B, only A streams)
    f32x4 xa0 = {0.f, 0.f, 0.f, 0.f};
    f32x4 xa1 = {0.f, 0.f, 0.f, 0.f};
    {
        const unsigned short* xb = Xb + (size_t)arow * Dq + kg * 8;
#pragma unroll
        for (int i = 0; i < 4; ++i) {
            bf16x8 A = *(const bf16x8*)(xb + (kq + 4 * i) * 32);
            xa0 = __builtin_amdgcn_mfma_f32_16x16x32_bf16(A, xb0[i], xa0, 0, 0, 0);
            xa1 = __builtin_amdgcn_mfma_f32_16x16x32_bf16(A, xb1[i], xa1, 0, 0, 0);
        }
    }

    const unsigned long long cntaddr = (unsigned long long)(bar + myxcd * 32);
    const unsigned long long myflag = (unsigned long long)(bar + 1024 + (myxcd * 32 + slot) * 32);

    for (int t = 0; t < Tq; ++t) {
        // h layout: [cslot 32][b 128][u 32] bf16 -> each wg writes one contiguous 1KB block
        const unsigned short* Hcur = Hb + (size_t)t * BHq;
        unsigned short* Hnxt = Hb + (size_t)(t + 1) * BHq;
        const unsigned short* hb = Hcur + (size_t)arow * 32 + kg * 8;

        f32x4 acc0 = xa0, acc1 = xa1;

        // h-part GEMM: reg-held B (chunks 28..47 slice) + LDS B (chunks 16..27 slice).
        // A-load for chunk c: Hcur[(c-16)*4096 + arow*32 + kg*8] (1024B/wave coalesced)
#pragma unroll
        for (int i = 7; i < 12; ++i) {
            int c = kq + 4 * i;
            bf16x8 A = *(const bf16x8*)(hb + (size_t)(c - 16) * 4096);
            acc0 = __builtin_amdgcn_mfma_f32_16x16x32_bf16(A, pb0[i - 7], acc0, 0, 0, 0);
            acc1 = __builtin_amdgcn_mfma_f32_16x16x32_bf16(A, pb1[i - 7], acc1, 0, 0, 0);
        }
#pragma unroll
        for (int i = 4; i < 7; ++i) {
            int c = kq + 4 * i;
            bf16x8 A = *(const bf16x8*)(hb + (size_t)(c - 16) * 4096);
            const unsigned short* lp = Wl + ((c - 16) * 128) * 40 + kg * 8;
            bf16x8 B0 = *(const bf16x8*)(lp + wlc0 * 40);
            bf16x8 B1 = *(const bf16x8*)(lp + wlc1 * 40);
            acc0 = __builtin_amdgcn_mfma_f32_16x16x32_bf16(A, B0, acc0, 0, 0, 0);
            acc1 = __builtin_amdgcn_mfma_f32_16x16x32_bf16(A, B1, acc1, 0, 0, 0);
        }

        // ALL waves write partials, bank-swizzled
#pragma unroll
        for (int r = 0; r < 4; ++r) {
            int w = kg * 4 + r;
            int u = ug * 8 + (c16 & 7);
            int g0 = (c16 >> 3);
            int up = (u + 8 * kg) & 31;
            redbuf[((w * 4 + g0) * 4 + kq) * 32 + up] = acc0[r];
            redbuf[((w * 4 + g0 + 2) * 4 + kq) * 32 + up] = acc1[r];
        }
        __syncthreads();  // (A) partials visible

        // ---- ALL-WAVE epilogue -> stage h row pairs in LDS (no global store here)
        if (lane < 32) {
            const int up = (uu + 8 * (wave >> 2)) & 31;
            float z[4];
#pragma unroll
            for (int g = 0; g < 4; ++g) {
                z[g] = redbuf[((wave * 4 + g) * 4 + 0) * 32 + up] +
                       redbuf[((wave * 4 + g) * 4 + 1) * 32 + up] +
                       redbuf[((wave * 4 + g) * 4 + 2) * 32 + up] +
                       redbuf[((wave * 4 + g) * 4 + 3) * 32 + up] + biasv[g];
            }
            float gi = sigm(z[0]);
            float gf = sigm(z[1]);
            float gg = tanh_f(z[2]);
            float go = sigm(z[3]);
            float cn = gf * creg0 + gi * gg;
            creg0 = cn;
            float hn = go * tanh_f(cn);
            unsigned hb16 = (unsigned)f2bf(hn);
            unsigned pv = (unsigned)__shfl_xor((int)hb16, 1, 64);
            if (!(uu & 1)) {
                hstage[wave * 16 + (uu >> 1)] = (hb16 & 0xffffu) | (pv << 16);
            }
        }
        __syncthreads();  // (B1) hstage complete

        // ---- wave 0: single wave-wide 1024B full-line store (plain write-back ->
        // lands dirty in local L2, NO RFO since every 128B line fully covered)
        if (wave == 0) {
            f32x4 v = *(const f32x4*)&hstage[lane * 4];
            *(f32x4*)(Hnxt + ((size_t)slot * 128 + rbase) * 32 + lane * 8) = v;
        }
        __syncthreads();  // (B2) wave0's store drained into local L2

        // ---- arrive: atomic add (fire-and-forget)
        if (tid == 0) {
            asm volatile("global_atomic_add %0, %1, off" ::"v"(cntaddr), "v"(1u) : "memory");
        }

        // ---- ALL waves: x-part prefetch for t+1 (overlaps barrier wait)
        if (t + 1 < Tq) {
            const unsigned short* xb = Xb + ((size_t)(t + 1) * Bq + arow) * Dq + kg * 8;
            xa0 = (f32x4){0.f, 0.f, 0.f, 0.f};
            xa1 = (f32x4){0.f, 0.f, 0.f, 0.f};
#pragma unroll
            for (int i = 0; i < 4; ++i) {
                bf16x8 A = *(const bf16x8*)(xb + (kq + 4 * i) * 32);
                xa0 = __builtin_amdgcn_mfma_f32_16x16x32_bf16(A, xb0[i], xa0, 0, 0, 0);
                xa1 = __builtin_amdgcn_mfma_f32_16x16x32_bf16(A, xb1[i], xa1, 0, 0, 0);
            }
        }

        // ---- wait: atomic-add-0 sc0 probes (RMW executes at L2, always fresh)
        if (tid == 0) {
            if (slot == 0) {
                const unsigned target = mytot * (unsigned)(t + 1);
                for (;;) {
                    unsigned old;
                    asm volatile("global_atomic_add %0, %1, %2, off sc0\n\ts_waitcnt vmcnt(0)"
                                 : "=v"(old)
                                 : "v"(cntaddr), "v"(0u)
                                 : "memory");
                    if (old >= target) break;
                    __builtin_amdgcn_s_sleep(1);
                }
                unsigned stepv = (unsigned)(t + 1);
#pragma unroll
                for (int s = 1; s < 32; ++s) {
                    unsigned long long fa = (unsigned long long)(bar + 1024 + (myxcd * 32 + s) * 32);
                    asm volatile("global_store_dword %0, %1, off sc0" ::"v"(fa), "v"(stepv) : "memory");
                }
            } else {
                for (;;) {
                    unsigned fv;
                    asm volatile("global_atomic_add %0, %1, %2, off sc0\n\ts_waitcnt vmcnt(0)"
                                 : "=v"(fv)
                                 : "v"(myflag), "v"(0u)
                                 : "memory");
                    if (fv >= (unsigned)(t + 1)) break;
                    __builtin_amdgcn_s_sleep(1);
                }
            }
            asm volatile("" ::: "memory");
        }
        __syncthreads();  // (C)
    }

    // ---- dense head: slots 0..15 each handle one local batch row
    // h layout: [jslot][b][u] -> element j = (tid>>5)*32 + (tid&31) = tid
    if (slot < 16) {
        const int b = rbase + slot;
        const unsigned short* hl = Hb + (size_t)Tq * BHq;
        float s = bf2f(hl[((size_t)(tid >> 5) * 128 + b) * 32 + (tid & 31)]) * dw[tid];
#pragma unroll
        for (int off = 32; off > 0; off >>= 1) s += __shfl_down(s, off, 64);
        if (lane == 0) red[wave] = s;
        __syncthreads();
        if (tid == 0) {
            float tot = db[0];
#pragma unroll
            for (int wv = 0; wv < 16; ++wv) tot += red[wv];
            out[b] = 1.f / (1.f + __expf(-tot));
        }
    }
}

extern "C" void kernel_launch(void* const* d_in, const int* in_sizes, int n_in,
                              void* d_out, int out_size, void* d_ws, size_t ws_size,
                              hipStream_t stream) {
    const float* X = (const float*)d_in[0];
    const float* Kw = (const float*)d_in[1];
    const float* Rw = (const float*)d_in[2];
    const float* bias = (const float*)d_in[3];
    const float* dw = (const float*)d_in[4];
    const float* db = (const float*)d_in[5];
    float* out = (float*)d_out;
    char* ws = (char*)d_ws;

    // workspace layout:
    //   Wp  bf16 fragment-packed [32][48][128][4][8]  @ 0           (12,582,912)
    //   Xb  bf16 [256][128][512]                      @ 12,582,912  (33,554,432)
    //   Hb  bf16 [257][32][128][32] rotating          @ 46,137,344  (67,371,008)
    //   bar u32 [17408]                               @ 113,508,352 (69,632)
    unsigned short* Wp = (unsigned short*)(ws);
    unsigned short* Xb = (unsigned short*)(ws + 12582912);
    unsigned short* Hb = (unsigned short*)(ws + 46137344);
    unsigned* bar = (unsigned*)(ws + 113508352);

    pack_w<<<dim3(128, 48), dim3(32, 8), 0, stream>>>(Kw, Rw, Wp);
    pack_x<<<8192, 256, 0, stream>>>(X, Xb);
    init_ws<<<512, 256, 0, stream>>>(Hb, bar);

    lstm_persist<<<NWG, NTHR, 0, stream>>>(Wp, Xb, bias, Hb, dw, db, out, bar);
}